// Round 8
// baseline (2278.815 us; speedup 1.0000x reference)
//
#include <hip/hip_runtime.h>
#include <hip/hip_bf16.h>

#define IN_CH 256
#define OUT_CH 64
#define RPB   128          // rows per fine bucket (b = r >> 7)
#define RSH   7
#define NFMAX 1024         // max fine buckets (n <= 131072)
#define CHUNK 6144         // edges per fine_scatter block (24 per thread)
#define CAPC  4096         // chunk_sort staging capacity (32 KB LDS)
#define ASTR  65           // LDS acc row stride (floats): bank-disjoint ds_add

// ---- bf16 helpers ----
__device__ __forceinline__ unsigned short f2bf(float f) {   // manual RNE (prep paths)
    unsigned u = __float_as_uint(f);
    u += 0x7fff + ((u >> 16) & 1);
    return (unsigned short)(u >> 16);
}
__device__ __forceinline__ unsigned short f2bf_hw(float f) { // HW cvt (pairs into v_cvt_pk_bf16_f32)
    __hip_bfloat16 h = __float2bfloat16(f);
    union { __hip_bfloat16 b; unsigned short u; } c;
    c.b = h;
    return c.u;
}
__device__ __forceinline__ float bf2f(unsigned short h) {
    return __uint_as_float((unsigned)h << 16);
}

using bfrag = __attribute__((ext_vector_type(8))) short;   // 8 bf16 (4 VGPRs)
using ffrag = __attribute__((ext_vector_type(4))) float;   // 4 fp32 acc
using f32x4 = __attribute__((ext_vector_type(4))) float;   // vector type for NT loads

// ---------------------------------------------------------------------------
// W pre-convert: fragment-major bf16 Wf (32 KB), written once.
// ---------------------------------------------------------------------------
__global__ __launch_bounds__(256) void wprep_kernel(
    const float* __restrict__ W, unsigned short* __restrict__ Wf)
{
    int i = blockIdx.x * 256 + threadIdx.x;   // 64 blocks x 256 = 16384
    int k  = i >> 6;
    int c  = i & 63;
    int ks = k >> 5;
    int kq = (k >> 3) & 3;
    int j  = k & 7;
    int nt = c >> 4;
    int lc = c & 15;
    Wf[(((ks * 4 + nt) * 64) + kq * 16 + lc) * 8 + j] = f2bf(W[i]);
}

// ---------------------------------------------------------------------------
// MFMA dense transform v4 (unchanged): 16 rows/wave, full-row NT prefetch.
// ---------------------------------------------------------------------------
__global__ __launch_bounds__(256) void gemm_mfma_kernel(
    const float* __restrict__ feat, const unsigned short* __restrict__ Wf,
    const float* __restrict__ bias, unsigned short* __restrict__ out, int n)
{
    const int wv   = threadIdx.x >> 6;
    const int lane = threadIdx.x & 63;
    const int quad = lane >> 4;
    const int lc   = lane & 15;

    const int rbase = blockIdx.x * 64 + wv * 16;
    const int lrow  = min(rbase + lc, n - 1);
    const f32x4* frow = (const f32x4*)(feat + (size_t)lrow * IN_CH);

    f32x4 a[16];
#pragma unroll
    for (int i = 0; i < 16; ++i) {
        int ks = i >> 1;
        int j  = i & 1;
        a[i] = __builtin_nontemporal_load(frow + ks * 8 + quad * 2 + j);
    }

    ffrag acc[4];
#pragma unroll
    for (int nt = 0; nt < 4; ++nt)
#pragma unroll
        for (int r = 0; r < 4; ++r) acc[nt][r] = 0.f;

#pragma unroll
    for (int ks = 0; ks < 8; ++ks) {
        f32x4 a0 = a[ks * 2 + 0];
        f32x4 a1 = a[ks * 2 + 1];
        bfrag af;
        af[0] = (short)f2bf_hw(a0[0]); af[1] = (short)f2bf_hw(a0[1]);
        af[2] = (short)f2bf_hw(a0[2]); af[3] = (short)f2bf_hw(a0[3]);
        af[4] = (short)f2bf_hw(a1[0]); af[5] = (short)f2bf_hw(a1[1]);
        af[6] = (short)f2bf_hw(a1[2]); af[7] = (short)f2bf_hw(a1[3]);
#pragma unroll
        for (int nt = 0; nt < 4; ++nt) {
            bfrag bf = *(const bfrag*)&Wf[(((ks * 4 + nt) * 64) + lane) * 8];
            acc[nt] = __builtin_amdgcn_mfma_f32_16x16x32_bf16(af, bf, acc[nt], 0, 0, 0);
        }
    }

#pragma unroll
    for (int nt = 0; nt < 4; ++nt) {
        float bv = bias[nt * 16 + lc];
#pragma unroll
        for (int r = 0; r < 4; ++r) {
            int orow = rbase + quad * 4 + r;
            if (orow < n) {
                float v = fmaxf(acc[nt][r] + bv, 0.f);
                out[(size_t)orow * OUT_CH + nt * 16 + lc] = f2bf_hw(v);
            }
        }
    }
}

// ---------------------------------------------------------------------------
// Edge bucketing: counting sort into 128-row dst buckets.
// Record: int2 { x = col | (row_in_bucket << 20), y = bits(val) }.
// (col < 2^17, rl < 2^7 -> fits. No rowptr / per-row sort needed anymore.)
// ---------------------------------------------------------------------------
__global__ __launch_bounds__(256) void fine_count_kernel(
    const int* __restrict__ rows, int* __restrict__ fineCnt,
    int nEdges, int nfine)
{
    __shared__ int h[NFMAX];
    const int t = threadIdx.x;
    for (int i = t; i < nfine; i += 256) h[i] = 0;
    __syncthreads();
    const int stride = gridDim.x * 256;
    for (int e = blockIdx.x * 256 + t; e < nEdges; e += stride)
        atomicAdd(&h[__builtin_nontemporal_load(rows + e) >> RSH], 1);
    __syncthreads();
    for (int i = t; i < nfine; i += 256) {
        int v = h[i];
        if (v) atomicAdd(&fineCnt[i], v);
    }
}

__global__ __launch_bounds__(256) void fine_scan_kernel(
    const int* __restrict__ fineCnt, int* __restrict__ fineBase,
    int* __restrict__ flushCursor, int nfine, int E)
{
    __shared__ int tmp[256];
    const int t = threadIdx.x;
    int v[4];
    int s = 0;
#pragma unroll
    for (int j = 0; j < 4; ++j) {
        int i = t * 4 + j;
        v[j] = (i < nfine) ? fineCnt[i] : 0;
        s += v[j];
    }
    tmp[t] = s;
    __syncthreads();
    for (int off = 1; off < 256; off <<= 1) {
        int x = (t >= off) ? tmp[t - off] : 0;
        __syncthreads();
        tmp[t] += x;
        __syncthreads();
    }
    int excl = tmp[t] - s;
#pragma unroll
    for (int j = 0; j < 4; ++j) {
        int i = t * 4 + j;
        if (i < nfine) { fineBase[i] = excl; flushCursor[i] = excl; }
        excl += v[j];
    }
    if (t == 0) fineBase[nfine] = E;
}

__global__ __launch_bounds__(256) void fine_scatter_kernel(
    const int* __restrict__ rows, const int* __restrict__ cols,
    const float* __restrict__ vals, int* __restrict__ flushCursor,
    int2* __restrict__ ebcv, int nEdges, int nfine)
{
    __shared__ int hist[NFMAX];
    __shared__ int lofs[NFMAX];
    __shared__ int gpos[NFMAX];
    __shared__ int cur[NFMAX];
    __shared__ int scanTmp[256];
    __shared__ int   sr[CHUNK];
    __shared__ int   sc[CHUNK];
    __shared__ float sv[CHUNK];

    const int t  = threadIdx.x;
    const int e0 = blockIdx.x * CHUNK;
    const int cnt_in = min(CHUNK, nEdges - e0);

    for (int i = t; i < nfine; i += 256) hist[i] = 0;
    __syncthreads();

    int   lr[CHUNK / 256];
    int   lc[CHUNK / 256];
    float lv[CHUNK / 256];
#pragma unroll
    for (int j = 0; j < CHUNK / 256; ++j) {
        int i = j * 256 + t;
        if (i < cnt_in) {
            lr[j] = __builtin_nontemporal_load(rows + e0 + i);
            lc[j] = __builtin_nontemporal_load(cols + e0 + i);
            lv[j] = __builtin_nontemporal_load(vals + e0 + i);
            atomicAdd(&hist[lr[j] >> RSH], 1);
        } else {
            lr[j] = -1;
        }
    }
    __syncthreads();

    // exclusive scan of hist, 4 bins per thread (nfine <= 1024)
    int v4[4];
    int s4 = 0;
#pragma unroll
    for (int j = 0; j < 4; ++j) {
        int i = t * 4 + j;
        v4[j] = (i < nfine) ? hist[i] : 0;
        s4 += v4[j];
    }
    scanTmp[t] = s4;
    __syncthreads();
    for (int off = 1; off < 256; off <<= 1) {
        int x = (t >= off) ? scanTmp[t - off] : 0;
        __syncthreads();
        scanTmp[t] += x;
        __syncthreads();
    }
    int excl = scanTmp[t] - s4;
#pragma unroll
    for (int j = 0; j < 4; ++j) {
        int i = t * 4 + j;
        if (i < nfine) lofs[i] = excl;
        excl += v4[j];
    }
    __syncthreads();

    for (int i = t; i < nfine; i += 256) {
        int h = hist[i];
        gpos[i] = h ? atomicAdd(&flushCursor[i], h) : 0;
        cur[i]  = lofs[i];
    }
    __syncthreads();

#pragma unroll
    for (int j = 0; j < CHUNK / 256; ++j) {
        if (lr[j] >= 0) {
            int bk = lr[j] >> RSH;
            int p  = atomicAdd(&cur[bk], 1);
            sr[p] = lr[j];
            sc[p] = lc[j];
            sv[p] = lv[j];
        }
    }
    __syncthreads();

    for (int i = t; i < cnt_in; i += 256) {
        int bk = sr[i] >> RSH;
        int rl = sr[i] & (RPB - 1);
        int p  = gpos[bk] + (i - lofs[bk]);
        ebcv[p] = make_int2(sc[i] | (rl << 20), __float_as_int(sv[i]));
    }
}

// ---------------------------------------------------------------------------
// chunk_sort: within each bucket, counting-sort edges by src chunk (c>>13,
// 1 MB windows). PURE PERF TRANSFORM: hop correctness does not depend on it.
// All blocks then sweep chunks in lockstep -> gathers hit the XCD-L2-resident
// rolling window instead of random 64 B lines from L3. In-place safe: all
// global reads complete before the barrier that precedes the writeback.
// ---------------------------------------------------------------------------
__global__ __launch_bounds__(256) void chunk_sort_kernel(
    int2* __restrict__ ebcv, const int* __restrict__ fineBase)
{
    __shared__ int  hist[16];
    __shared__ int  curb[16];
    __shared__ int2 st[CAPC];            // 32 KB staging

    const int t  = threadIdx.x;
    const int lo = fineBase[blockIdx.x];
    const int hi = fineBase[blockIdx.x + 1];
    const int cnt = hi - lo;
    if (cnt > CAPC) return;              // perf-only fallback: leave unsorted

    if (t < 16) hist[t] = 0;
    __syncthreads();
    for (int e = lo + t; e < hi; e += 256)
        atomicAdd(&hist[(ebcv[e].x & 0xFFFFF) >> 13], 1);
    __syncthreads();
    if (t == 0) {
        int run = 0;
        for (int i = 0; i < 16; ++i) { curb[i] = run; run += hist[i]; }
    }
    __syncthreads();
    for (int e = lo + t; e < hi; e += 256) {
        int2 ed = ebcv[e];
        int  ck = (ed.x & 0xFFFFF) >> 13;
        int  p  = atomicAdd(&curb[ck], 1);
        st[p] = ed;
    }
    __syncthreads();
    for (int i = t; i < cnt; i += 256)
        ebcv[lo + i] = st[i];
}

// ---------------------------------------------------------------------------
// SpMM hop v4: one block per 128-row bucket, LDS fp32 accumulation.
// 16 quarter-waves x 16-edge two-phase batches (round-7 gather structure:
// 64 edges in flight per wave). ds_add stride ASTR=65 -> quarter-waves land
// in disjoint bank classes (2 lanes/bank = free, m136).
// ---------------------------------------------------------------------------
template<bool DST_F32>
__global__ __launch_bounds__(256) void spmm_lds_kernel(
    const int2* __restrict__ epack, const int* __restrict__ fineBase,
    const unsigned short* __restrict__ src, void* __restrict__ dstv, int n)
{
    __shared__ float acc[RPB * ASTR];    // 33.3 KB
    const int t  = threadIdx.x;
    const int qw = t >> 4;               // 16 quarter-waves
    const int ch = (t & 15) * 4;         // 4 channels per lane

    for (int i = t; i < RPB * ASTR; i += 256) acc[i] = 0.f;
    __syncthreads();

    const int lo = fineBase[blockIdx.x];
    const int hi = fineBase[blockIdx.x + 1];

    for (int b = lo + qw * 16; b < hi; b += 256) {
        int2  p[16];
        float v[16];
#pragma unroll
        for (int j = 0; j < 16; ++j) {
            int e = b + j;
            p[j] = epack[min(e, hi - 1)];          // contiguous broadcast, cheap
            v[j] = (e < hi) ? __int_as_float(p[j].y) : 0.f;
        }
        ushort4 s[16];
#pragma unroll
        for (int j = 0; j < 16; ++j) {
            if (b + j < hi) {                       // qw-uniform guard: no waste
                int c = p[j].x & 0xFFFFF;
                s[j] = *(const ushort4*)(src + ((size_t)c << 6) + ch);
            } else {
                s[j] = make_ushort4(0, 0, 0, 0);
            }
        }
#pragma unroll
        for (int j = 0; j < 16; ++j) {
            if (b + j < hi) {
                int    rl = p[j].x >> 20;
                float* a  = &acc[rl * ASTR + ch];
                atomicAdd(a + 0, v[j] * bf2f(s[j].x));
                atomicAdd(a + 1, v[j] * bf2f(s[j].y));
                atomicAdd(a + 2, v[j] * bf2f(s[j].z));
                atomicAdd(a + 3, v[j] * bf2f(s[j].w));
            }
        }
    }
    __syncthreads();

    // writeout: 128 rows x 64 ch (scalar LDS reads: ASTR odd -> no b128 claim)
    const int r0 = blockIdx.x << RSH;
    for (int i = t; i < RPB * 16; i += 256) {
        int row = i >> 4, seg = (i & 15) * 4;
        if (r0 + row < n) {
            const float* a = &acc[row * ASTR + seg];
            if constexpr (DST_F32) {
                float4 o;
                o.x = a[0]; o.y = a[1]; o.z = a[2]; o.w = a[3];
                *(float4*)((float*)dstv + ((size_t)(r0 + row) << 6) + seg) = o;
            } else {
                ushort4 o;
                o.x = f2bf_hw(a[0]);
                o.y = f2bf_hw(a[1]);
                o.z = f2bf_hw(a[2]);
                o.w = f2bf_hw(a[3]);
                *(ushort4*)((unsigned short*)dstv + ((size_t)(r0 + row) << 6) + seg) = o;
            }
        }
    }
}

// ---------------------------------------------------------------------------
extern "C" void kernel_launch(void* const* d_in, const int* in_sizes, int n_in,
                              void* d_out, int out_size, void* d_ws, size_t ws_size,
                              hipStream_t stream)
{
    const int*   adj  = (const int*)d_in[0];    // [2, E] int32
    const float* vals = (const float*)d_in[1];  // [E]
    const float* feat = (const float*)d_in[2];  // [N, 256]
    const float* W    = (const float*)d_in[3];  // [256, 64]
    const float* bias = (const float*)d_in[4];  // [1, 64]

    const int E = in_sizes[1];
    const int n = in_sizes[2] / IN_CH;
    const int* rows = adj;       // destination rows
    const int* cols = adj + E;   // gather sources

    const int nfine = (n + RPB - 1) >> RSH;   // fine buckets of 128 rows

    // ---- workspace layout (256 B aligned regions; ebcv persists all hops,
    //      so no aliasing with B0/B1) ----
    char* ws = (char*)d_ws;
    size_t off = 0;
    auto alloc = [&](size_t bytes) {
        void* p = ws + off;
        off += (bytes + 255) & ~(size_t)255;
        return p;
    };
    unsigned short* B0 = (unsigned short*)alloc((size_t)n * OUT_CH * sizeof(unsigned short));
    unsigned short* B1 = (unsigned short*)alloc((size_t)n * OUT_CH * sizeof(unsigned short));
    int2*  ebcv        = (int2*) alloc((size_t)E * sizeof(int2));
    int*   fineCnt     = (int*)  alloc(NFMAX * sizeof(int));
    int*   fineBase    = (int*)  alloc((NFMAX + 1) * sizeof(int));
    int*   flushCursor = (int*)  alloc(NFMAX * sizeof(int));
    unsigned short* Wf = (unsigned short*)alloc((size_t)IN_CH * OUT_CH * sizeof(unsigned short));

    float* out = (float*)d_out;

    // ---- W pre-convert (independent, tiny) ----
    wprep_kernel<<<(IN_CH * OUT_CH) / 256, 256, 0, stream>>>(W, Wf);

    // ---- bucket edges (counting sort to 128-row dst buckets) ----
    hipMemsetAsync(fineCnt, 0, (size_t)nfine * sizeof(int), stream);
    fine_count_kernel<<<256, 256, 0, stream>>>(rows, fineCnt, E, nfine);
    fine_scan_kernel<<<1, 256, 0, stream>>>(fineCnt, fineBase, flushCursor,
                                            nfine, E);
    fine_scatter_kernel<<<(E + CHUNK - 1) / CHUNK, 256, 0, stream>>>(
        rows, cols, vals, flushCursor, ebcv, E, nfine);

    // ---- order each bucket's edges by src chunk (perf-only transform) ----
    chunk_sort_kernel<<<nfine, 256, 0, stream>>>(ebcv, fineBase);

    // ---- dense transform (MFMA, bf16 output, full-row prefetch) ----
    gemm_mfma_kernel<<<(n + 63) / 64, 256, 0, stream>>>(feat, Wf, bias, B0, n);

    // ---- 3 SpMM hops (LDS-accumulated, chunk-localized gathers) ----
    spmm_lds_kernel<false><<<nfine, 256, 0, stream>>>(ebcv, fineBase, B0, B1, n);
    spmm_lds_kernel<false><<<nfine, 256, 0, stream>>>(ebcv, fineBase, B1, B0, n);
    spmm_lds_kernel<true ><<<nfine, 256, 0, stream>>>(ebcv, fineBase, B0, out, n);
}